// Round 7
// baseline (212.885 us; speedup 1.0000x reference)
//
#include <hip/hip_runtime.h>

typedef int   v4i  __attribute__((ext_vector_type(4)));
typedef int   v16i __attribute__((ext_vector_type(16)));
typedef float v4f  __attribute__((ext_vector_type(4)));

#define NIMG 64
#define Cc   64
#define NPIX 3136
#define W8SZ (9 * 2 * 2 * 64 * 16)   // 36864 B per conv: [t][hc][cohalf][lane][16]

#define RBK   4                  // output rows per block
#define TILES 14                 // 56 / RBK row-tiles per image
#define XROWS 8                  // RBK + 4 staged x rows
#define MROWS 6                  // RBK + 2 mid rows
#define WPITCH 80                // LDS bytes per pixel (64 data + 16 pad)
#define ROWP  (58 * WPITCH)      // LDS bytes per padded row = 4640

#define MFMA32(A, B, C) __builtin_amdgcn_mfma_i32_32x32x32_i8(A, B, C, 0, 0, 0)

__device__ __forceinline__ float clamp8(float v) {
    return fminf(fmaxf(v, -128.f), 127.f);
}

// ---- pack OIHW fp32 weights into MFMA B-fragment order ---------------------
// B(K=ci x N=co) per lane: co = cohalf*32 + (lane&31), ci = hc*32 + (lane>>5)*16 + j
__global__ __launch_bounds__(256) void qbb_pack_w(
    const float* __restrict__ w1, const float* __restrict__ w2,
    signed char* __restrict__ w8)
{
    int idx  = blockIdx.x * 256 + threadIdx.x;   // 0 .. 2*W8SZ-1
    int conv = idx / W8SZ;
    int r    = idx - conv * W8SZ;
    const float* src = conv ? w2 : w1;
    int j    = r & 15;
    int lane = (r >> 4) & 63;
    int ch   = (r >> 10) & 1;    // cohalf
    int hc   = (r >> 11) & 1;    // ci-half
    int t    = r >> 12;          // tap 0..8
    int co   = ch * 32 + (lane & 31);
    int ci   = hc * 32 + ((lane >> 5) << 4) + j;
    w8[idx] = (signed char)(int)src[(co * 64 + ci) * 9 + t];
}

// ---- fully fused: stage x -> conv1+bn1 (mid in LDS) -> conv2+bn2+add -------
__global__ __launch_bounds__(256, 2) void qbb_fused(
    const float* __restrict__ x, const signed char* __restrict__ w8,
    const float* __restrict__ b1, const float* __restrict__ g1,
    const float* __restrict__ be1,
    const float* __restrict__ b2, const float* __restrict__ g2,
    const float* __restrict__ be2,
    const int* __restrict__ p_zx, const int* __restrict__ p_zm,
    const int* __restrict__ p_M0c1, const int* __restrict__ p_shc1,
    const int* __restrict__ M0b1, const int* __restrict__ shb1,
    const int* __restrict__ p_M0c2, const int* __restrict__ p_shc2,
    const int* __restrict__ M0b2, const int* __restrict__ shb2,
    const int* __restrict__ p_M0a1, const int* __restrict__ p_sha1,
    const int* __restrict__ p_M0a2, const int* __restrict__ p_sha2,
    const int* __restrict__ p_zadd,
    float* __restrict__ out)
{
    __shared__ signed char xs[XROWS * ROWP];   // 37120 B: x-zx int8, padded
    __shared__ signed char ms[MROWS * ROWP];   // 27840 B: mid int8, padded

    const int tid  = threadIdx.x;
    const int lane = tid & 63, wid = tid >> 6;
    const int blk  = blockIdx.x;
    const int n    = blk / TILES;
    const int m0   = (blk - n * TILES) * RBK;  // first output row (content)

    const int cohalf = wid & 1;          // co 0..31 or 32..63
    const int tpar   = wid >> 1;         // tile partition (0/1)
    const int lpx    = lane & 31;        // px-in-tile / co-in-B
    const int lci    = lane >> 5;        // k-subgroup
    const int co     = cohalf * 32 + lpx;

    // ---- zero left/right pad columns of xs and ms ----
    if (tid < 112) {
        if (tid < 64) {                  // xs: 8 rows x 2 cols x 4 chunks
            int r = tid >> 3, col = (tid >> 2) & 1, ch = tid & 3;
            *(v4i*)&xs[r * ROWP + (col * 57) * WPITCH + ch * 16] = v4i{0, 0, 0, 0};
        } else {                         // ms: 6 rows x 2 cols x 4 chunks
            int t2 = tid - 64;
            int r = t2 >> 3, col = (t2 >> 2) & 1, ch = t2 & 3;
            *(v4i*)&ms[r * ROWP + (col * 57) * WPITCH + ch * 16] = v4i{0, 0, 0, 0};
        }
    }

    // ---- per-lane channel constants (co fixed per lane!) ----
    const float zx   = (float)(*p_zx);
    const float zm   = (float)(*p_zm);
    const float sc1  = ldexpf((float)(*p_M0c1), -31 - (*p_shc1));
    const float sc2  = ldexpf((float)(*p_M0c2), -31 - (*p_shc2));
    const float sa1  = ldexpf((float)(*p_M0a1), -31 - (*p_sha1));
    const float sa2  = ldexpf((float)(*p_M0a2), -31 - (*p_sha2));
    const float zadd = (float)(*p_zadd);
    const float bb1 = b1[co], gg1 = g1[co], bev1 = be1[co];
    const float sb1f = ldexpf((float)M0b1[co], -31 - shb1[co]);
    const float bb2 = b2[co], gg2 = g2[co], bev2 = be2[co];
    const float sb2f = ldexpf((float)M0b2[co], -31 - shb2[co]);

    // ---- weight B-fragments (reused array: conv1 then conv2) ----
    v4i wB[9][2];
    auto LOADW = [&](int conv) {
#pragma unroll
        for (int t = 0; t < 9; ++t)
#pragma unroll
            for (int h = 0; h < 2; ++h)
                wB[t][h] = *(const v4i*)(w8 + (((conv * 9 + t) * 2 + h) * 2 + cohalf) * 1024
                                            + lane * 16);
    };
    LOADW(0);

    // ---- stage x rows m0-2 .. m0+5 as int8 (x - zx); OOB rows -> zeros ----
    for (int e = tid; e < XROWS * 16 * 56; e += 256) {
        int L   = e / (16 * 56);
        int rem = e - L * (16 * 56);
        int cq  = rem / 56;
        int w   = rem - cq * 56;
        int hh  = m0 - 2 + L;
        unsigned pk = 0;
        if ((unsigned)hh < 56u) {
            const float* xp = x + ((size_t)(n * Cc + cq * 4) * 56 + hh) * 56 + w;
#pragma unroll
            for (int j = 0; j < 4; ++j) {
                int bv = (int)(xp[(size_t)j * NPIX] - zx);
                pk |= (unsigned)(bv & 255) << (8 * j);
            }
        }
        *(unsigned*)&xs[L * ROWP + (w + 1) * WPITCH + cq * 4] = pk;
    }
    __syncthreads();   // xs + pads ready

    // ---- conv1: A = patch(32px x 32ci), B = weights -> ms int8 ----
    auto C1_EPI = [&](int T, const v16i& acc) {
#pragma unroll
        for (int rg = 0; rg < 4; ++rg) {
#pragma unroll
            for (int r = 0; r < 4; ++r) {
                int pxo = T * 32 + rg * 8 + lci * 4 + r;
                if (pxo < 336) {
                    int rmo = pxo / 56, wo = pxo - rmo * 56;
                    int m = m0 - 1 + rmo;
                    int iv = 0;
                    if ((unsigned)m < 56u) {
                        float aa = (float)acc[rg * 4 + r] + bb1;
                        float v  = clamp8(rintf(aa * sc1) + zm);
                        float tt = (v - zm) * gg1 + bev1;
                        float u  = clamp8(rintf(tt * sb1f) + zm);
                        iv = (int)(u - zm);
                    }
                    ms[rmo * ROWP + (wo + 1) * WPITCH + co] = (signed char)iv;
                }
            }
        }
    };
    auto C1_PAIR = [&](int TA, int TB, bool hasB) {
        v16i accA = {0,0,0,0,0,0,0,0,0,0,0,0,0,0,0,0};
        v16i accB = {0,0,0,0,0,0,0,0,0,0,0,0,0,0,0,0};
        int pxA = TA * 32 + lpx;  int pca = pxA < 336 ? pxA : 335;
        int rmA = pca / 56, wA = pca - rmA * 56;
        int baA = rmA * ROWP + wA * WPITCH + lci * 16;
        int baB = baA;
        if (hasB) {
            int pxB = TB * 32 + lpx;  int pcb = pxB < 336 ? pxB : 335;
            int rmB = pcb / 56, wBq = pcb - rmB * 56;
            baB = rmB * ROWP + wBq * WPITCH + lci * 16;
        }
#pragma unroll
        for (int t = 0; t < 9; ++t) {
            int kh = t / 3, kw = t - kh * 3;
            int o = kh * ROWP + kw * WPITCH;
            accA = MFMA32(*(const v4i*)&xs[baA + o],      wB[t][0], accA);
            accB = MFMA32(*(const v4i*)&xs[baB + o],      wB[t][0], accB);
            accA = MFMA32(*(const v4i*)&xs[baA + o + 32], wB[t][1], accA);
            accB = MFMA32(*(const v4i*)&xs[baB + o + 32], wB[t][1], accB);
        }
        C1_EPI(TA, accA);
        if (hasB) C1_EPI(TB, accB);
    };
    for (int T = tpar; T < 11; T += 4)
        C1_PAIR(T, T + 2, T + 2 < 11);

    LOADW(1);          // conv2 weights into same regs (overlap barrier wait)
    __syncthreads();   // ms ready

    // ---- conv2 + requant + bn2 + requant + shortcut add -> out (f32) ----
    auto C2_EPI = [&](int T, const v16i& acc) {
#pragma unroll
        for (int rg = 0; rg < 4; ++rg) {
            int px4 = T * 32 + rg * 8 + lci * 4;
            int ro = px4 / 56, wo = px4 - ro * 56;
            v4f res;
#pragma unroll
            for (int r = 0; r < 4; ++r) {
                float aa   = (float)acc[rg * 4 + r] + bb2;
                float v    = clamp8(rintf(aa * sc2) + zm);
                float tt   = (v - zm) * gg2 + bev2;
                float u    = clamp8(rintf(tt * sb2f) + zm);
                float outr = rintf((u - zm) * sa2);
                float idr  = rintf((float)xs[(ro + 2) * ROWP + (wo + 1 + r) * WPITCH + co] * sa1);
                res[r] = clamp8(idr + outr + zadd);
            }
            *(v4f*)(out + ((size_t)(n * Cc) + co) * NPIX + (m0 + ro) * 56 + wo) = res;
        }
    };
    auto C2_PAIR = [&](int TA, int TB, bool hasB) {
        v16i accA = {0,0,0,0,0,0,0,0,0,0,0,0,0,0,0,0};
        v16i accB = {0,0,0,0,0,0,0,0,0,0,0,0,0,0,0,0};
        int pxA = TA * 32 + lpx;
        int rmA = pxA / 56, wA = pxA - rmA * 56;
        int baA = rmA * ROWP + wA * WPITCH + lci * 16;
        int baB = baA;
        if (hasB) {
            int pxB = TB * 32 + lpx;
            int rmB = pxB / 56, wBq = pxB - rmB * 56;
            baB = rmB * ROWP + wBq * WPITCH + lci * 16;
        }
#pragma unroll
        for (int t = 0; t < 9; ++t) {
            int kh = t / 3, kw = t - kh * 3;
            int o = kh * ROWP + kw * WPITCH;
            accA = MFMA32(*(const v4i*)&ms[baA + o],      wB[t][0], accA);
            accB = MFMA32(*(const v4i*)&ms[baB + o],      wB[t][0], accB);
            accA = MFMA32(*(const v4i*)&ms[baA + o + 32], wB[t][1], accA);
            accB = MFMA32(*(const v4i*)&ms[baB + o + 32], wB[t][1], accB);
        }
        C2_EPI(TA, accA);
        if (hasB) C2_EPI(TB, accB);
    };
    {
        int hi = tpar ? 7 : 4;
        for (int T = tpar * 4; T < hi; T += 2)
            C2_PAIR(T, T + 1, T + 1 < hi);
    }
}

extern "C" void kernel_launch(void* const* d_in, const int* in_sizes, int n_in,
                              void* d_out, int out_size, void* d_ws, size_t ws_size,
                              hipStream_t stream) {
    const float* x   = (const float*)d_in[0];
    const float* w1  = (const float*)d_in[1];
    const float* b1  = (const float*)d_in[2];
    const float* w2  = (const float*)d_in[3];
    const float* b2  = (const float*)d_in[4];
    const float* g1  = (const float*)d_in[5];
    const float* be1 = (const float*)d_in[6];
    const float* g2  = (const float*)d_in[7];
    const float* be2 = (const float*)d_in[8];
    const int* z_x   = (const int*)d_in[9];
    const int* z_mid = (const int*)d_in[10];
    const int* M0c1  = (const int*)d_in[11];
    const int* shc1  = (const int*)d_in[12];
    const int* M0b1  = (const int*)d_in[13];
    const int* shb1  = (const int*)d_in[14];
    const int* M0c2  = (const int*)d_in[15];
    const int* shc2  = (const int*)d_in[16];
    const int* M0b2  = (const int*)d_in[17];
    const int* shb2  = (const int*)d_in[18];
    const int* M0a1  = (const int*)d_in[19];
    const int* sha1  = (const int*)d_in[20];
    const int* M0a2  = (const int*)d_in[21];
    const int* sha2  = (const int*)d_in[22];
    const int* z_add = (const int*)d_in[23];

    signed char* w8 = (signed char*)d_ws;   // 2 x 36 KB packed B-fragments

    qbb_pack_w<<<dim3(2 * W8SZ / 256), dim3(256), 0, stream>>>(w1, w2, w8);
    qbb_fused<<<dim3(NIMG * TILES), dim3(256), 0, stream>>>(
        x, w8, b1, g1, be1, b2, g2, be2,
        z_x, z_mid, M0c1, shc1, M0b1, shb1, M0c2, shc2, M0b2, shb2,
        M0a1, sha1, M0a2, sha2, z_add, (float*)d_out);
}